// Round 1
// baseline (334.322 us; speedup 1.0000x reference)
//
#include <hip/hip_runtime.h>

// ---------------------------------------------------------------------------
// DiffAttention forward, bf16 MFMA pipeline.  B=4 T=1024 C=1024 H=16 hs=64 dv=128.
//   1. cast x -> bf16; transpose-cast weights -> W^T[n][k] bf16
//   2. proj GEMM (m97-style global_load_lds): proj[4096][6144] = xb @ wcat^T
//   3. transpose v slice -> vt[(b,h)][dim][token]
//   4. attention: TRANSPOSED-S chaining: S^T = K Q^T (16x16x32) so the P^T
//      C-frag [key=quad*4+reg][q=lane&15] feeds PV (O^T += V^T P^T, 16x16x16)
//      directly from registers -> NO P LDS round-trip. Softmax state per-lane
//      scalar (q = lane&15); max reduction = in-lane tree + shfl_xor(16,32);
//      row-sum l comes FREE from a ones-row MFMA fragment in PV.
//      Defer-rescale (T13): skip O-rescale while __all(mx <= m + 44.4) (P<=256).
//      ONE qblk per block (1024 blocks, big-first LPT order) for 3 blocks/CU;
//      blockIdx%8 == h&7 keeps same-(b,h) blocks on one XCD. Fused subLN.
//   5. out GEMM: out[4096][1024] fp32 = yln @ wc^T
// MFMA mappings (HW-verified): A[m=lane&15][k=quad*8+j] (K=32) / quad*4+j
// (K=16); B^T[n=lane&15][k=same]; C/D: col=lane&15, row=quad*4+reg.
// R8 lesson: the #error guard fired on the HOST pass (amdgcn builtins are
// invisible to __has_builtin there) — #else must be a host-safe dummy.
// R9 (this round): SQ_LDS_BANK_CONFLICT ~6.7M is the INHERENT b64/b128
// wide-read aliasing floor (4 resp. 8 lanes/bank = data-volume minimum) —
// swizzling cannot reduce it; do not chase it.
// ---------------------------------------------------------------------------

#define T_SEQ 1024
#define NH 16
#define DV 128
#define NPROJ 6144
#define KSTR 72  // K/V LDS row stride (elements)

typedef __bf16 bf16_t;
typedef __bf16 bf16x8 __attribute__((ext_vector_type(8)));
typedef __bf16 bf16x4 __attribute__((ext_vector_type(4)));
typedef short s16x4 __attribute__((ext_vector_type(4)));
typedef float f32x4 __attribute__((ext_vector_type(4)));

#define LAMBDA_INIT 0.35550906759096928f
#define ONE_MINUS_LI 0.6444909324090307f
#define LOG2E 1.4426950408889634f
// defer-rescale threshold in RAW score units: 8 / (0.125*log2e) ~= 44.36
#define RTHR 44.36f

// 16x16x16 bf16 MFMA (K=16). Device pass resolves a real builtin; the host
// pass (where __has_builtin is false for amdgcn builtins) gets a dummy that
// is never executed.
#if __has_builtin(__builtin_amdgcn_mfma_f32_16x16x16_bf16)
#define MFMA16(a, b, c) __builtin_amdgcn_mfma_f32_16x16x16_bf16(a, b, c, 0, 0, 0)
#elif __has_builtin(__builtin_amdgcn_mfma_f32_16x16x16bf16_1k)
#define MFMA16(a, b, c)                                                       \
  __builtin_amdgcn_mfma_f32_16x16x16bf16_1k(                                  \
      __builtin_bit_cast(s16x4, a), __builtin_bit_cast(s16x4, b), c, 0, 0, 0)
#else
#define MFMA16(a, b, c) (c)  // host pass only — never executed
#endif

// async global->LDS, 16B/lane (gemm only).
#define GLDS(g, l)                                                            \
  __builtin_amdgcn_global_load_lds(                                           \
      (const __attribute__((address_space(1))) void*)(g),                     \
      (__attribute__((address_space(3))) void*)(l), 16, 0, 0)

// ---------------- workspace layout (bytes) ----------------
static const size_t OFF_WCAT = 0;                                  // 6144x1024 bf16
static const size_t OFF_XB = OFF_WCAT + (size_t)6144 * 1024 * 2;   // 4096x1024 bf16
static const size_t OFF_WCT = OFF_XB + (size_t)4096 * 1024 * 2;    // 1024x2048 bf16
static const size_t OFF_PROJ = OFF_WCT + (size_t)2048 * 1024 * 2;  // 4096x6144 bf16
static const size_t OFF_VT = OFF_PROJ + (size_t)4096 * 6144 * 2;   // 64*128*1024 bf16
static const size_t OFF_YLN = OFF_VT + (size_t)64 * 128 * 1024 * 2;// 4096x2048 bf16
static const size_t OFF_LAM = OFF_YLN + (size_t)4096 * 2048 * 2;   // 16 f32

// ---------------- elementwise cast x -> bf16 ----------------
__global__ void __launch_bounds__(256) cast_x(const float* __restrict__ x,
                                              bf16_t* __restrict__ o) {
  const int i = (blockIdx.x * 256 + threadIdx.x) * 4;
  float4 v = *(const float4*)(x + i);
  bf16x4 r = {(bf16_t)v.x, (bf16_t)v.y, (bf16_t)v.z, (bf16_t)v.w};
  *(bf16x4*)(o + i) = r;
}

// ---------------- transpose-cast weight W[K][N] fp32 -> Wt[row0+n][k] bf16 ----
__device__ __forceinline__ void tcast_body(const float* __restrict__ W,
                                           bf16_t* __restrict__ Wt, int K,
                                           int N, int row0) {
  __shared__ float tile[32][33];
  const int k0 = blockIdx.x * 32, n0 = blockIdx.y * 32;
  const int tx = threadIdx.x & 31, ty = threadIdx.x >> 5;  // 32x8
#pragma unroll
  for (int i = 0; i < 32; i += 8)
    tile[ty + i][tx] = W[(long)(k0 + ty + i) * N + n0 + tx];
  __syncthreads();
#pragma unroll
  for (int i = 0; i < 32; i += 8)
    Wt[(long)(row0 + n0 + ty + i) * K + k0 + tx] = (bf16_t)tile[tx][ty + i];
}

__global__ void __launch_bounds__(256) tcast_w(const float* __restrict__ W,
                                               bf16_t* __restrict__ Wt, int K,
                                               int N, int row0) {
  tcast_body(W, Wt, K, N, row0);
}

// fused: the four 1024x1024 q/k weights in one launch (z selects)
__global__ void __launch_bounds__(256) tcast_w4(const float* __restrict__ W0,
                                                const float* __restrict__ W1,
                                                const float* __restrict__ W2,
                                                const float* __restrict__ W3,
                                                bf16_t* __restrict__ Wt) {
  const float* Ws[4] = {W0, W1, W2, W3};
  tcast_body(Ws[blockIdx.z], Wt, 1024, 1024, blockIdx.z * 1024);
}

// ---------------- per-head lambda ----------------
__global__ void lam_kernel(const float* __restrict__ lq1,
                           const float* __restrict__ lk1,
                           const float* __restrict__ lq2,
                           const float* __restrict__ lk2,
                           float* __restrict__ lam) {
  const int h = threadIdx.x;
  if (h < NH) {
    float d1 = 0.f, d2 = 0.f;
    for (int i = 0; i < 64; ++i) {
      d1 += lq1[h * 64 + i] * lk1[h * 64 + i];
      d2 += lq2[h * 64 + i] * lk2[h * 64 + i];
    }
    lam[h] = expf(d1) - expf(d2) + LAMBDA_INIT;
  }
}

// ---------------- GEMM (m97 structure): C[M][N] = A[M][K] @ Bt[N][K]^T -------
#define BM 128
#define BN 128
#define BK 32

template <typename OutT>
__global__ void __launch_bounds__(256) gemm_bt(const bf16_t* __restrict__ A,
                                               const bf16_t* __restrict__ Bt,
                                               OutT* __restrict__ C, int M,
                                               int N, int K) {
  __shared__ __align__(16) bf16_t As[BM * BK];
  __shared__ __align__(16) bf16_t Bs[BN * BK];
  const int tid = threadIdx.x;
  const int w = tid >> 6;
  const int lane = tid & 63;
  const int quad = lane >> 4, l16 = lane & 15;
  const int m0 = blockIdx.y * BM, n0 = blockIdx.x * BN;
  const int wm = (w >> 1) * 64, wn = (w & 1) * 64;
  const int srow = tid >> 2;       // 0..63
  const int scol = (tid & 3) * 8;  // 0,8,16,24

  const bf16_t* Ag0 = A + (long)(m0 + srow) * K + scol;
  const bf16_t* Ag1 = Ag0 + (long)64 * K;
  const bf16_t* Bg0 = Bt + (long)(n0 + srow) * K + scol;
  const bf16_t* Bg1 = Bg0 + (long)64 * K;
  bf16_t* lA0 = As + tid * 8;  // == srow*32 + scol
  bf16_t* lA1 = As + 2048 + tid * 8;
  bf16_t* lB0 = Bs + tid * 8;
  bf16_t* lB1 = Bs + 2048 + tid * 8;

  f32x4 acc[4][4] = {};

  for (int k0 = 0; k0 < K; k0 += BK) {
    GLDS(Ag0 + k0, lA0);
    GLDS(Ag1 + k0, lA1);
    GLDS(Bg0 + k0, lB0);
    GLDS(Bg1 + k0, lB1);
    __syncthreads();
    bf16x8 af[4], bfr[4];
#pragma unroll
    for (int t = 0; t < 4; ++t) {
      af[t] = *(const bf16x8*)(As + (wm + t * 16 + l16) * BK + quad * 8);
      bfr[t] = *(const bf16x8*)(Bs + (wn + t * 16 + l16) * BK + quad * 8);
    }
#pragma unroll
    for (int mt = 0; mt < 4; ++mt)
#pragma unroll
      for (int nt = 0; nt < 4; ++nt)
        acc[mt][nt] = __builtin_amdgcn_mfma_f32_16x16x32_bf16(
            af[mt], bfr[nt], acc[mt][nt], 0, 0, 0);
    __syncthreads();
  }

#pragma unroll
  for (int mt = 0; mt < 4; ++mt)
#pragma unroll
    for (int nt = 0; nt < 4; ++nt) {
      const int col = n0 + wn + nt * 16 + l16;
#pragma unroll
      for (int i = 0; i < 4; ++i) {
        const int row = m0 + wm + mt * 16 + quad * 4 + i;
        C[(long)row * N + col] = (OutT)acc[mt][nt][i];
      }
    }
}

// ---------------- transpose v slice of proj -> vt[(b,h)][d][t] ----------------
__global__ void __launch_bounds__(256) transpose_v(const bf16_t* __restrict__ proj,
                                                   bf16_t* __restrict__ vt) {
  __shared__ bf16_t tile[32][34];
  const int bh = blockIdx.z;
  const int b = bh >> 4, h = bh & 15;
  const int t0 = blockIdx.x * 32, d0 = blockIdx.y * 32;
  const int tx = threadIdx.x & 31, ty = threadIdx.x >> 5;
  const bf16_t* src = proj + (long)(b * T_SEQ) * NPROJ + 4096 + h * 128;
#pragma unroll
  for (int i = 0; i < 32; i += 8)
    tile[ty + i][tx] = src[(long)(t0 + ty + i) * NPROJ + d0 + tx];
  __syncthreads();
  bf16_t* dst = vt + ((long)(b * NH + h) * DV) * T_SEQ;
#pragma unroll
  for (int i = 0; i < 32; i += 8)
    dst[(long)(d0 + ty + i) * T_SEQ + t0 + tx] = tile[tx][ty + i];
}

// ---------------- attention: transposed-S, one qblk per block --------------
// grid: (1024). x -> qi = x>>6 (qblk = 15-qi, big blocks dispatch FIRST for
// LPT balance), bh = x&63 (b = bh>>4, h = bh&15). blockIdx%8 == h&7 -> all
// blocks of one (b,h) land on one XCD for K/V L2 reuse. 4 waves; wave w owns
// q rows q0..q0+15 (q = lane&15 for ALL its fragments).
__global__ void __launch_bounds__(256) attn_kernel(const bf16_t* __restrict__ proj,
                                                   const bf16_t* __restrict__ vt,
                                                   const float* __restrict__ lamp,
                                                   bf16_t* __restrict__ yln) {
  const int x = blockIdx.x;
  const int qblk = 15 - (x >> 6);
  const int bh = x & 63;
  const int b = bh >> 4, h = bh & 15;
  const int tid = threadIdx.x;
  const int w = tid >> 6, lane = tid & 63;
  const int quad = lane >> 4, l16 = lane & 15;
  const long bT = (long)b * T_SEQ;

  __shared__ __align__(16) bf16_t Ks1[64 * KSTR];  // [key][dim]
  __shared__ __align__(16) bf16_t Ks2[64 * KSTR];
  __shared__ __align__(16) bf16_t Vs[DV * KSTR];   // [dim][key]

  // ---- staging source pointers ----
  const bf16_t* gK1 =
      proj + (bT + (tid >> 3)) * (long)NPROJ + h * 64 + 2048 + (tid & 7) * 8;
  const bf16_t* gK2 = gK1 + 1024;
  const bf16_t* vbase = vt + ((long)(b * NH + h) * DV) * T_SEQ;
  const bf16_t* gV = vbase + (long)(tid >> 3) * T_SEQ + (tid & 7) * 8;
  const int kw0 = (tid >> 3) * KSTR + (tid & 7) * 8;  // rows 0..31; +32*KSTR

  const float sc = 0.125f * LOG2E;  // 1/sqrt(64) folded with log2(e)
  const float lam = lamp[h];

  const int q0 = qblk * 64 + w * 16;
  const int qg = q0 + l16;  // this lane's q row (all fragments)

  // ---- Q fragments (B-operand role; same per-lane layout as A) ----
  const bf16_t* qrow = proj + (bT + qg) * (long)NPROJ + h * 64;
  bf16x8 aq1[2], aq2[2];
  aq1[0] = *(const bf16x8*)(qrow + quad * 8);
  aq1[1] = *(const bf16x8*)(qrow + 32 + quad * 8);
  aq2[0] = *(const bf16x8*)(qrow + 1024 + quad * 8);
  aq2[1] = *(const bf16x8*)(qrow + 1024 + 32 + quad * 8);

  f32x4 O1[8] = {}, O2[8] = {};  // O^T[d=f*16+quad*4+reg][q=l16]
  float m1 = -3.0e38f, m2 = -3.0e38f, l1 = 0.f, l2 = 0.f;

  const int kend_blk = qblk * 64 + 64;
  const int kend_w = q0 + 16;

  const bf16x4 one4 = {(bf16_t)1.0f, (bf16_t)1.0f, (bf16_t)1.0f, (bf16_t)1.0f};

  // ---- prime the register pipeline with tile kt=0 ----
  bf16x8 rK1[2], rK2[2], rV[4];
  rK1[0] = *(const bf16x8*)(gK1);
  rK1[1] = *(const bf16x8*)(gK1 + (long)32 * NPROJ);
  rK2[0] = *(const bf16x8*)(gK2);
  rK2[1] = *(const bf16x8*)(gK2 + (long)32 * NPROJ);
#pragma unroll
  for (int j = 0; j < 4; ++j)
    rV[j] = *(const bf16x8*)(gV + (long)(32 * j) * T_SEQ);

  for (int kt = 0; kt < kend_blk; kt += 64) {
    // ---- commit staged registers to LDS ----
    *(bf16x8*)(Ks1 + kw0) = rK1[0];
    *(bf16x8*)(Ks1 + kw0 + 32 * KSTR) = rK1[1];
    *(bf16x8*)(Ks2 + kw0) = rK2[0];
    *(bf16x8*)(Ks2 + kw0 + 32 * KSTR) = rK2[1];
#pragma unroll
    for (int j = 0; j < 4; ++j)
      *(bf16x8*)(Vs + kw0 + j * 32 * KSTR) = rV[j];
    __syncthreads();

    // ---- prefetch next tile into registers (overlaps compute) ----
    if (kt + 64 < kend_blk) {
      const long ko = (long)(kt + 64) * NPROJ;
      rK1[0] = *(const bf16x8*)(gK1 + ko);
      rK1[1] = *(const bf16x8*)(gK1 + ko + (long)32 * NPROJ);
      rK2[0] = *(const bf16x8*)(gK2 + ko);
      rK2[1] = *(const bf16x8*)(gK2 + ko + (long)32 * NPROJ);
#pragma unroll
      for (int j = 0; j < 4; ++j)
        rV[j] = *(const bf16x8*)(gV + kt + 64 + (long)(32 * j) * T_SEQ);
    }

    if (kt < kend_w) {
      // ---- S^T = K Q^T : A=K-frag (from LDS), B=Q-frag (regs) ----
      // S^T frag c: [key = kt+c*16+quad*4+reg][q = l16]  (RAW scores)
      f32x4 s1[4], s2[4];
#pragma unroll
      for (int c = 0; c < 4; ++c) {
        const bf16_t* kr1 = Ks1 + (c * 16 + l16) * KSTR;
        const bf16_t* kr2 = Ks2 + (c * 16 + l16) * KSTR;
        bf16x8 ka0 = *(const bf16x8*)(kr1 + quad * 8);
        bf16x8 ka1 = *(const bf16x8*)(kr1 + 32 + quad * 8);
        f32x4 z = {};
        z = __builtin_amdgcn_mfma_f32_16x16x32_bf16(ka0, aq1[0], z, 0, 0, 0);
        z = __builtin_amdgcn_mfma_f32_16x16x32_bf16(ka1, aq1[1], z, 0, 0, 0);
        s1[c] = z;
        bf16x8 kb0 = *(const bf16x8*)(kr2 + quad * 8);
        bf16x8 kb1 = *(const bf16x8*)(kr2 + 32 + quad * 8);
        f32x4 z2 = {};
        z2 = __builtin_amdgcn_mfma_f32_16x16x32_bf16(kb0, aq2[0], z2, 0, 0, 0);
        z2 = __builtin_amdgcn_mfma_f32_16x16x32_bf16(kb1, aq2[1], z2, 0, 0, 0);
        s2[c] = z2;
      }
      // ---- causal mask on RAW scores + in-lane TREE max (short dep chain) --
      const bool need_mask = (kt + 63 > q0);
      if (need_mask) {
#pragma unroll
        for (int c = 0; c < 4; ++c)
#pragma unroll
          for (int i = 0; i < 4; ++i) {
            const int key = kt + c * 16 + quad * 4 + i;
            if (key > qg) {
              s1[c][i] = -1e30f;
              s2[c][i] = -1e30f;
            }
          }
      }
      float t1[4], t2[4];
#pragma unroll
      for (int c = 0; c < 4; ++c) {
        t1[c] = fmaxf(fmaxf(s1[c][0], s1[c][1]), fmaxf(s1[c][2], s1[c][3]));
        t2[c] = fmaxf(fmaxf(s2[c][0], s2[c][1]), fmaxf(s2[c][2], s2[c][3]));
      }
      float mx1 = fmaxf(fmaxf(t1[0], t1[1]), fmaxf(t1[2], t1[3]));
      float mx2 = fmaxf(fmaxf(t2[0], t2[1]), fmaxf(t2[2], t2[3]));
      // cross-quad max (lanes sharing l16)
      mx1 = fmaxf(mx1, __shfl_xor(mx1, 16));
      mx1 = fmaxf(mx1, __shfl_xor(mx1, 32));
      mx2 = fmaxf(mx2, __shfl_xor(mx2, 16));
      mx2 = fmaxf(mx2, __shfl_xor(mx2, 32));
      // ---- defer-rescale: only pay the O/l rescale when max really grew ----
      if (!__all((mx1 <= m1 + RTHR) && (mx2 <= m2 + RTHR))) {
        const float mn1 = fmaxf(m1, mx1), mn2 = fmaxf(m2, mx2);
        const float al1 = exp2f((m1 - mn1) * sc);
        const float al2 = exp2f((m2 - mn2) * sc);
        m1 = mn1;
        m2 = mn2;
#pragma unroll
        for (int f = 0; f < 8; ++f)
#pragma unroll
          for (int i = 0; i < 4; ++i) {
            O1[f][i] *= al1;
            O2[f][i] *= al2;
          }
        l1 *= al1;
        l2 *= al2;
      }
      // ---- P = exp2(fma(s,sc,-m*sc)), packed bf16x4 per c (PV B-operand) ----
      const float ms1 = m1 * sc, ms2 = m2 * sc;
      bf16x4 pc1[4], pc2[4];
#pragma unroll
      for (int c = 0; c < 4; ++c)
#pragma unroll
        for (int i = 0; i < 4; ++i) {
          pc1[c][i] = (bf16_t)exp2f(fmaf(s1[c][i], sc, -ms1));
          pc2[c][i] = (bf16_t)exp2f(fmaf(s2[c][i], sc, -ms2));
        }
      // ---- PV: O^T += V^T P^T; row-sum l via ones-row MFMA fragment ----
      f32x4 la1 = {}, la2 = {};
#pragma unroll
      for (int c = 0; c < 4; ++c) {
        la1 = MFMA16(one4, pc1[c], la1);
        la2 = MFMA16(one4, pc2[c], la2);
#pragma unroll
        for (int f = 0; f < 8; ++f) {
          bf16x4 va =
              *(const bf16x4*)(Vs + (f * 16 + l16) * KSTR + c * 16 + quad * 4);
          O1[f] = MFMA16(va, pc1[c], O1[f]);
          O2[f] = MFMA16(va, pc2[c], O2[f]);
        }
      }
      l1 += la1[0];
      l2 += la2[0];
    }
    __syncthreads();
  }

  // ---- combine streams, subLN over 128 dims, scale, store bf16 ----
  const float inv1 = 1.0f / l1, inv2 = lam / l2;
  float sm = 0.f, sq = 0.f;
#pragma unroll
  for (int f = 0; f < 8; ++f)
#pragma unroll
    for (int i = 0; i < 4; ++i) {
      float y = O1[f][i] * inv1 - O2[f][i] * inv2;
      O1[f][i] = y;
      sm += y;
      sq += y * y;
    }
  sm += __shfl_xor(sm, 16);
  sm += __shfl_xor(sm, 32);
  sq += __shfl_xor(sq, 16);
  sq += __shfl_xor(sq, 32);
  const float mu = sm * (1.0f / 128.0f);
  const float var = sq * (1.0f / 128.0f) - mu * mu;
  const float rs = rsqrtf(var + 1e-5f) * ONE_MINUS_LI;
  bf16_t* dst = yln + (bT + qg) * (long)2048 + h * 128 + quad * 4;
#pragma unroll
  for (int f = 0; f < 8; ++f) {
    bf16x4 o = {(bf16_t)((O1[f][0] - mu) * rs), (bf16_t)((O1[f][1] - mu) * rs),
                (bf16_t)((O1[f][2] - mu) * rs), (bf16_t)((O1[f][3] - mu) * rs)};
    *(bf16x4*)(dst + f * 16) = o;
  }
}

// ---------------------------------------------------------------------------
extern "C" void kernel_launch(void* const* d_in, const int* in_sizes, int n_in,
                              void* d_out, int out_size, void* d_ws,
                              size_t ws_size, hipStream_t stream) {
  const float* x = (const float*)d_in[0];
  const float* Wq1 = (const float*)d_in[1];
  const float* Wq2 = (const float*)d_in[2];
  const float* Wk1 = (const float*)d_in[3];
  const float* Wk2 = (const float*)d_in[4];
  const float* Wv = (const float*)d_in[5];
  const float* Wc = (const float*)d_in[6];
  const float* lq1 = (const float*)d_in[7];
  const float* lk1 = (const float*)d_in[8];
  const float* lq2 = (const float*)d_in[9];
  const float* lk2 = (const float*)d_in[10];
  float* out = (float*)d_out;

  char* ws = (char*)d_ws;
  bf16_t* wcat = (bf16_t*)(ws + OFF_WCAT);
  bf16_t* xb = (bf16_t*)(ws + OFF_XB);
  bf16_t* wct = (bf16_t*)(ws + OFF_WCT);
  bf16_t* projb = (bf16_t*)(ws + OFF_PROJ);
  bf16_t* vtb = (bf16_t*)(ws + OFF_VT);
  bf16_t* ylnb = (bf16_t*)(ws + OFF_YLN);
  float* lamp = (float*)(ws + OFF_LAM);

  cast_x<<<4096, 256, 0, stream>>>(x, xb);
  tcast_w4<<<dim3(32, 32, 4), 256, 0, stream>>>(Wq1, Wq2, Wk1, Wk2, wcat);
  tcast_w<<<dim3(32, 64), 256, 0, stream>>>(Wv, wcat, 1024, 2048, 4096);
  tcast_w<<<dim3(64, 32), 256, 0, stream>>>(Wc, wct, 2048, 1024, 0);
  lam_kernel<<<1, 64, 0, stream>>>(lq1, lk1, lq2, lk2, lamp);

  // proj = xb @ wcat^T : M=4096 N=6144 K=1024
  gemm_bt<bf16_t><<<dim3(48, 32), 256, 0, stream>>>(xb, wcat, projb, 4096, 6144, 1024);
  transpose_v<<<dim3(32, 4, 64), 256, 0, stream>>>(projb, vtb);
  attn_kernel<<<dim3(1024), 256, 0, stream>>>(projb, vtb, lamp, ylnb);
  // out = yln @ wc^T : M=4096 N=1024 K=2048
  gemm_bt<float><<<dim3(8, 32), 256, 0, stream>>>(ylnb, wct, out, 4096, 1024, 2048);
}